// Round 1
// baseline (626.965 us; speedup 1.0000x reference)
//
#include <hip/hip_runtime.h>
#include <hip/hip_bf16.h>
#include <stdint.h>

#define B_  256
#define C_  512
#define S_  256
#define NH  8
#define DH  64

typedef float f32x4 __attribute__((ext_vector_type(4)));
typedef short s16x8 __attribute__((ext_vector_type(8)));

static __device__ __forceinline__ unsigned short f2bf(float f) {
  union { float f; unsigned u; } v; v.f = f;
  unsigned r = v.u + 0x7FFFu + ((v.u >> 16) & 1u);
  return (unsigned short)(r >> 16);
}

static __device__ __forceinline__ void gload_lds16(const void* g, void* l) {
  __builtin_amdgcn_global_load_lds((const __attribute__((address_space(1))) void*)g,
                                   (__attribute__((address_space(3))) void*)l,
                                   16, 0, 0);
}

// ---------------- prep_w: W [C][512] f32 -> W^T [512][C] bf16 -------------
__global__ __launch_bounds__(256) void prep_w(const float* __restrict__ Wq,
                                              const float* __restrict__ Wk,
                                              const float* __restrict__ Wv,
                                              const float* __restrict__ Wf,
                                              unsigned short* __restrict__ Wqkvt,
                                              unsigned short* __restrict__ Wft) {
  int mat = blockIdx.z;
  const float* src = (mat == 0) ? Wq : (mat == 1) ? Wk : (mat == 2) ? Wv : Wf;
  unsigned short* dst = (mat < 3) ? (Wqkvt + (size_t)mat * 512 * 512) : Wft;
  int n0 = blockIdx.x * 64, c0 = blockIdx.y * 64;
  __shared__ float tile[64][65];
  int t = threadIdx.x;
  int tr = t >> 4;          // 0..15
  int tc = (t & 15) * 4;    // 0..60
#pragma unroll
  for (int i = 0; i < 4; ++i) {
    int c = tr + i * 16;
    float4 v = *(const float4*)&src[(size_t)(c0 + c) * 512 + n0 + tc];
    tile[c][tc + 0] = v.x; tile[c][tc + 1] = v.y;
    tile[c][tc + 2] = v.z; tile[c][tc + 3] = v.w;
  }
  __syncthreads();
#pragma unroll
  for (int i = 0; i < 4; ++i) {
    int n = tr + i * 16;
    ushort4 o;
    o.x = f2bf(tile[tc + 0][n]); o.y = f2bf(tile[tc + 1][n]);
    o.z = f2bf(tile[tc + 2][n]); o.w = f2bf(tile[tc + 3][n]);
    *(ushort4*)&dst[(size_t)(n0 + n) * 512 + c0 + tc] = o;
  }
}

// ---------------- prep_x: x [B][C][S] f32 -> xs [B][S][C] bf16 ------------
__global__ __launch_bounds__(256) void prep_x(const float* __restrict__ x,
                                              unsigned short* __restrict__ xs) {
  int b = blockIdx.z, s0 = blockIdx.x * 64, c0 = blockIdx.y * 64;
  __shared__ float tile[64][65];
  int t = threadIdx.x;
  int tr = t >> 4, tc = (t & 15) * 4;
  const float* xb = x + (size_t)b * C_ * S_;
#pragma unroll
  for (int i = 0; i < 4; ++i) {
    int c = tr + i * 16;
    float4 v = *(const float4*)&xb[(size_t)(c0 + c) * S_ + s0 + tc];
    tile[c][tc + 0] = v.x; tile[c][tc + 1] = v.y;
    tile[c][tc + 2] = v.z; tile[c][tc + 3] = v.w;
  }
  __syncthreads();
  unsigned short* xsb = xs + (size_t)b * S_ * C_;
#pragma unroll
  for (int i = 0; i < 4; ++i) {
    int s = tr + i * 16;
    ushort4 o;
    o.x = f2bf(tile[tc + 0][s]); o.y = f2bf(tile[tc + 1][s]);
    o.z = f2bf(tile[tc + 2][s]); o.w = f2bf(tile[tc + 3][s]);
    *(ushort4*)&xsb[(size_t)(s0 + s) * C_ + c0 + tc] = o;
  }
}

// ---------------- qkv_gemm: [256 s x 512 c] @ [512 c x 1536 n] ------------
// tile 128x128, 4 waves (2x2), K-step 64, linear LDS + XOR swizzle fed by
// global_load_lds w/ pre-swizzled source.
__global__ __launch_bounds__(256) void qkv_gemm(const unsigned short* __restrict__ xs,
                                                const unsigned short* __restrict__ Wqkvt,
                                                const float* __restrict__ bq,
                                                const float* __restrict__ bk,
                                                const float* __restrict__ bv,
                                                unsigned short* __restrict__ qout,
                                                unsigned short* __restrict__ kout,
                                                unsigned short* __restrict__ vout) {
  int b = blockIdx.z, mt = blockIdx.y, nt = blockIdx.x;
  __shared__ unsigned short As[128 * 64];   // rows s, 64 k, swizzled
  __shared__ unsigned short Bs[128 * 64];   // rows n, 64 k, swizzled
  int t = threadIdx.x, lane = t & 63, w = t >> 6;
  int wr = w >> 1, wc = w & 1;
  f32x4 acc[4][4] = {};
  const unsigned short* xsb = xs + ((size_t)b * S_ + mt * 128) * C_;
  const unsigned short* wt = Wqkvt + (size_t)nt * 128 * C_;
  for (int ks = 0; ks < 8; ++ks) {
    __syncthreads();
#pragma unroll
    for (int i = 0; i < 4; ++i) {
      int ch = (w * 4 + i) * 64 + lane;
      int r = ch >> 3, g = ch & 7;
      int gs = g ^ (r & 7);
      gload_lds16(xsb + (size_t)r * C_ + ks * 64 + gs * 8, (char*)As + (w * 4 + i) * 1024);
      gload_lds16(wt + (size_t)r * C_ + ks * 64 + gs * 8, (char*)Bs + (w * 4 + i) * 1024);
    }
    __syncthreads();
#pragma unroll
    for (int kk = 0; kk < 2; ++kk) {
      s16x8 af[4], bfrag[4];
#pragma unroll
      for (int fi = 0; fi < 4; ++fi) {
        int r = wr * 64 + fi * 16 + (lane & 15);
        int slot = (kk * 4 + (lane >> 4)) ^ (r & 7);
        af[fi] = *(const s16x8*)((const char*)As + r * 128 + slot * 16);
      }
#pragma unroll
      for (int fj = 0; fj < 4; ++fj) {
        int r = wc * 64 + fj * 16 + (lane & 15);
        int slot = (kk * 4 + (lane >> 4)) ^ (r & 7);
        bfrag[fj] = *(const s16x8*)((const char*)Bs + r * 128 + slot * 16);
      }
#pragma unroll
      for (int fi = 0; fi < 4; ++fi)
#pragma unroll
        for (int fj = 0; fj < 4; ++fj)
          acc[fi][fj] = __builtin_amdgcn_mfma_f32_16x16x32_bf16(af[fi], bfrag[fj], acc[fi][fj], 0, 0, 0);
    }
  }
  // epilogue: +bias, write bf16 to q/k/v [B][NH][S][DH]
  int s_base = mt * 128 + wr * 64;
#pragma unroll
  for (int fj = 0; fj < 4; ++fj) {
    int n_glob = nt * 128 + wc * 64 + fj * 16;
    int sel = n_glob >> 9;
    int within = n_glob & 511;
    int h = within >> 6, dbase = within & 63;
    const float* bias = (sel == 0) ? bq : (sel == 1) ? bk : bv;
    float bias_v = bias[within + (lane & 15)];
    unsigned short* dst = (sel == 0) ? qout : (sel == 1) ? kout : vout;
    unsigned short* dhead = dst + ((size_t)b * NH + h) * S_ * DH;
    int d = dbase + (lane & 15);
#pragma unroll
    for (int fi = 0; fi < 4; ++fi) {
      int srow = s_base + fi * 16 + (lane >> 4) * 4;
#pragma unroll
      for (int rg = 0; rg < 4; ++rg)
        dhead[(size_t)(srow + rg) * DH + d] = f2bf(acc[fi][fj][rg] + bias_v);
    }
  }
}

// ---------------- attn: per (b,h) flash-style, 4 waves x 64 q-rows --------
__global__ __launch_bounds__(256) void attn(const unsigned short* __restrict__ q,
                                            const unsigned short* __restrict__ k,
                                            const unsigned short* __restrict__ v,
                                            unsigned short* __restrict__ o) {
  int h = blockIdx.x, b = blockIdx.y;
  const unsigned short* qh = q + ((size_t)b * NH + h) * S_ * DH;
  const unsigned short* kh = k + ((size_t)b * NH + h) * S_ * DH;
  const unsigned short* vh = v + ((size_t)b * NH + h) * S_ * DH;
  __shared__ unsigned short Ks[64 * 72];    // [kj][d] padded
  __shared__ unsigned short Vt[64 * 72];    // [d][kj] padded
  __shared__ unsigned short P[4][64 * 72];  // per-wave P tile [qi][kj]
  int t = threadIdx.x, lane = t & 63, w = t >> 6;
  // Q fragments in registers
  s16x8 qf[4][2];
#pragma unroll
  for (int fi = 0; fi < 4; ++fi)
#pragma unroll
    for (int kk = 0; kk < 2; ++kk) {
      int row = w * 64 + fi * 16 + (lane & 15);
      qf[fi][kk] = *(const s16x8*)&qh[(size_t)row * DH + kk * 32 + (lane >> 4) * 8];
    }
  f32x4 acco[4][4] = {};
  float m_run[4][4], l_run[4][4];
#pragma unroll
  for (int i = 0; i < 4; ++i)
#pragma unroll
    for (int j = 0; j < 4; ++j) { m_run[i][j] = -1e30f; l_run[i][j] = 0.f; }

  const float SCL = 0.125f * 1.44269504089f;  // logits scale in log2 units

  for (int kb = 0; kb < 4; ++kb) {
    __syncthreads();
    {   // stage K block: 64 rows x 128B, coalesced
#pragma unroll
      for (int j = 0; j < 2; ++j) {
        int ch = t + 256 * j;
        int r = ch >> 3, g = ch & 7;
        *(uint4*)((char*)Ks + r * 144 + g * 16) =
            *(const uint4*)((const char*)(kh + (size_t)(kb * 64 + r) * DH) + g * 16);
      }
      // stage V block transposed: thread row i, 16 d's (conflict-free LDS writes)
      int i = t & 63, dq = t >> 6;
      const unsigned short* vs = vh + (size_t)(kb * 64 + i) * DH + dq * 16;
      union { uint4 v4; unsigned short u[8]; } a0, a1;
      a0.v4 = *(const uint4*)(vs);
      a1.v4 = *(const uint4*)(vs + 8);
#pragma unroll
      for (int j = 0; j < 8; ++j) {
        Vt[(dq * 16 + j) * 72 + i] = a0.u[j];
        Vt[(dq * 16 + 8 + j) * 72 + i] = a1.u[j];
      }
    }
    __syncthreads();
    // S = Q K^T  (raw, scale folded into exp)
    f32x4 accs[4][4] = {};
#pragma unroll
    for (int kk = 0; kk < 2; ++kk) {
      s16x8 kf[4];
#pragma unroll
      for (int fj = 0; fj < 4; ++fj) {
        int r = fj * 16 + (lane & 15);
        kf[fj] = *(const s16x8*)((const char*)Ks + r * 144 + kk * 64 + (lane >> 4) * 16);
      }
#pragma unroll
      for (int fi = 0; fi < 4; ++fi)
#pragma unroll
        for (int fj = 0; fj < 4; ++fj)
          accs[fi][fj] = __builtin_amdgcn_mfma_f32_16x16x32_bf16(qf[fi][kk], kf[fj], accs[fi][fj], 0, 0, 0);
    }
    // online softmax per row (rows live in lane>>4 groups; cols in lane&15 x fj)
#pragma unroll
    for (int fi = 0; fi < 4; ++fi) {
#pragma unroll
      for (int rg = 0; rg < 4; ++rg) {
        float mx = fmaxf(fmaxf(accs[fi][0][rg], accs[fi][1][rg]),
                         fmaxf(accs[fi][2][rg], accs[fi][3][rg]));
#pragma unroll
        for (int off = 1; off < 16; off <<= 1) mx = fmaxf(mx, __shfl_xor(mx, off, 64));
        float mnew = fmaxf(m_run[fi][rg], mx);
        float alpha = exp2f((m_run[fi][rg] - mnew) * SCL);
        m_run[fi][rg] = mnew;
        float lsum = 0.f;
#pragma unroll
        for (int fj = 0; fj < 4; ++fj) {
          float p = exp2f((accs[fi][fj][rg] - mnew) * SCL);
          accs[fi][fj][rg] = p;
          lsum += p;
        }
#pragma unroll
        for (int off = 1; off < 16; off <<= 1) lsum += __shfl_xor(lsum, off, 64);
        l_run[fi][rg] = l_run[fi][rg] * alpha + lsum;
#pragma unroll
        for (int fd = 0; fd < 4; ++fd) acco[fi][fd][rg] *= alpha;
      }
    }
    // write P (bf16) to this wave's LDS tile
#pragma unroll
    for (int fi = 0; fi < 4; ++fi)
#pragma unroll
      for (int fj = 0; fj < 4; ++fj)
#pragma unroll
        for (int rg = 0; rg < 4; ++rg) {
          int row = fi * 16 + (lane >> 4) * 4 + rg;
          int col = fj * 16 + (lane & 15);
          P[w][row * 72 + col] = f2bf(accs[fi][fj][rg]);
        }
    __syncthreads();  // make P visible across lanes (and keeps waves in step)
    // O += P V
#pragma unroll
    for (int kk = 0; kk < 2; ++kk) {
      s16x8 pf[4], vf[4];
#pragma unroll
      for (int fi = 0; fi < 4; ++fi) {
        int r = fi * 16 + (lane & 15);
        pf[fi] = *(const s16x8*)((const char*)P[w] + r * 144 + kk * 64 + (lane >> 4) * 16);
      }
#pragma unroll
      for (int fd = 0; fd < 4; ++fd) {
        int r = fd * 16 + (lane & 15);
        vf[fd] = *(const s16x8*)((const char*)Vt + r * 144 + kk * 64 + (lane >> 4) * 16);
      }
#pragma unroll
      for (int fi = 0; fi < 4; ++fi)
#pragma unroll
        for (int fd = 0; fd < 4; ++fd)
          acco[fi][fd] = __builtin_amdgcn_mfma_f32_16x16x32_bf16(pf[fi], vf[fd], acco[fi][fd], 0, 0, 0);
    }
  }
  // finalize: divide by l, store o [B][S][C] bf16 at column h*64
  unsigned short* ob = o + (size_t)b * S_ * C_ + h * DH;
#pragma unroll
  for (int fi = 0; fi < 4; ++fi)
#pragma unroll
    for (int rg = 0; rg < 4; ++rg) {
      float inv = 1.0f / l_run[fi][rg];
      int srow = w * 64 + fi * 16 + (lane >> 4) * 4 + rg;
#pragma unroll
      for (int fd = 0; fd < 4; ++fd) {
        int d = fd * 16 + (lane & 15);
        ob[(size_t)srow * C_ + d] = f2bf(acco[fi][fd][rg] * inv);
      }
    }
}

// ------------- proj_gn: y^T = Wf^T o^T (+bf +x), fused GroupNorm ----------
// block: 128 c x 256 s per batch; 8 waves (2c x 4s); output [B][C][S] f32
__global__ __launch_bounds__(512) void proj_gn(const unsigned short* __restrict__ o,
                                               const unsigned short* __restrict__ Wft,
                                               const float* __restrict__ bfp,
                                               const float* __restrict__ x,
                                               const float* __restrict__ gnw,
                                               const float* __restrict__ gnb,
                                               float* __restrict__ out) {
  int b = blockIdx.y, ct = blockIdx.x;
  __shared__ unsigned short As[128 * 72];   // Wf^T rows c
  __shared__ unsigned short Bs[256 * 72];   // o rows s
  __shared__ float red_s[128], red_q[128];
  __shared__ float mu_s[8], rs_s[8];
  int t = threadIdx.x, lane = t & 63, w = t >> 6;
  int wc = w >> 2, wsq = w & 3;
  if (t < 128) { red_s[t] = 0.f; red_q[t] = 0.f; }
  f32x4 acc[4][4] = {};
  const unsigned short* wt = Wft + (size_t)ct * 128 * C_;
  const unsigned short* ob = o + (size_t)b * S_ * C_;
  for (int ks = 0; ks < 8; ++ks) {
    __syncthreads();
#pragma unroll
    for (int i = 0; i < 2; ++i) {
      int ch = t + i * 512;
      int r = ch >> 3, g = ch & 7;
      *(uint4*)((char*)As + r * 144 + g * 16) =
          *(const uint4*)((const char*)(wt + (size_t)r * C_ + ks * 64) + g * 16);
    }
#pragma unroll
    for (int i = 0; i < 4; ++i) {
      int ch = t + i * 512;
      int r = ch >> 3, g = ch & 7;
      *(uint4*)((char*)Bs + r * 144 + g * 16) =
          *(const uint4*)((const char*)(ob + (size_t)r * C_ + ks * 64) + g * 16);
    }
    __syncthreads();
#pragma unroll
    for (int kk = 0; kk < 2; ++kk) {
      s16x8 af[4], bfrag[4];
#pragma unroll
      for (int fi = 0; fi < 4; ++fi) {
        int r = wc * 64 + fi * 16 + (lane & 15);
        af[fi] = *(const s16x8*)((const char*)As + r * 144 + kk * 64 + (lane >> 4) * 16);
      }
#pragma unroll
      for (int fj = 0; fj < 4; ++fj) {
        int r = wsq * 64 + fj * 16 + (lane & 15);
        bfrag[fj] = *(const s16x8*)((const char*)Bs + r * 144 + kk * 64 + (lane >> 4) * 16);
      }
#pragma unroll
      for (int fi = 0; fi < 4; ++fi)
#pragma unroll
        for (int fj = 0; fj < 4; ++fj)
          acc[fi][fj] = __builtin_amdgcn_mfma_f32_16x16x32_bf16(af[fi], bfrag[fj], acc[fi][fj], 0, 0, 0);
    }
  }
  // epilogue: y = acc + bf[c] + x[b][c][s]; accumulate group stats
  const float* xb = x + (size_t)b * C_ * S_;
  int c_base = ct * 128 + wc * 64;
  int s_base = wsq * 64;
#pragma unroll
  for (int fi = 0; fi < 4; ++fi)
#pragma unroll
    for (int rg = 0; rg < 4; ++rg) {
      int c = c_base + fi * 16 + (lane >> 4) * 4 + rg;
      float bias_v = bfp[c];
      float psum = 0.f, psq = 0.f;
#pragma unroll
      for (int fj = 0; fj < 4; ++fj) {
        int s = s_base + fj * 16 + (lane & 15);
        float y = acc[fi][fj][rg] + bias_v + xb[(size_t)c * S_ + s];
        acc[fi][fj][rg] = y;
        psum += y; psq += y * y;
      }
#pragma unroll
      for (int off = 1; off < 16; off <<= 1) {
        psum += __shfl_xor(psum, off, 64);
        psq += __shfl_xor(psq, off, 64);
      }
      if ((lane & 15) == 0) {
        int cl = c - ct * 128;
        atomicAdd(&red_s[cl], psum);
        atomicAdd(&red_q[cl], psq);
      }
    }
  __syncthreads();
  if (t < 8) {
    float s = 0.f, qq = 0.f;
#pragma unroll
    for (int i = 0; i < 16; ++i) { s += red_s[t * 16 + i]; qq += red_q[t * 16 + i]; }
    float mu = s * (1.0f / 4096.0f);
    float var = qq * (1.0f / 4096.0f) - mu * mu;
    mu_s[t] = mu;
    rs_s[t] = rsqrtf(var + 1e-5f);
  }
  __syncthreads();
  float* outb = out + (size_t)b * C_ * S_;
#pragma unroll
  for (int fi = 0; fi < 4; ++fi)
#pragma unroll
    for (int rg = 0; rg < 4; ++rg) {
      int c = c_base + fi * 16 + (lane >> 4) * 4 + rg;
      int gl = (c - ct * 128) >> 4;
      float mu = mu_s[gl], rs = rs_s[gl];
      float gw = gnw[c], gb = gnb[c];
#pragma unroll
      for (int fj = 0; fj < 4; ++fj) {
        int s = s_base + fj * 16 + (lane & 15);
        outb[(size_t)c * S_ + s] = (acc[fi][fj][rg] - mu) * rs * gw + gb;
      }
    }
}

extern "C" void kernel_launch(void* const* d_in, const int* in_sizes, int n_in,
                              void* d_out, int out_size, void* d_ws, size_t ws_size,
                              hipStream_t stream) {
  const float* x   = (const float*)d_in[0];
  const float* Wq  = (const float*)d_in[1];
  const float* bq  = (const float*)d_in[2];
  const float* Wk  = (const float*)d_in[3];
  const float* bk  = (const float*)d_in[4];
  const float* Wv  = (const float*)d_in[5];
  const float* bv  = (const float*)d_in[6];
  const float* Wf  = (const float*)d_in[7];
  const float* bf  = (const float*)d_in[8];
  const float* gnw = (const float*)d_in[9];
  const float* gnb = (const float*)d_in[10];

  char* ws = (char*)d_ws;
  // ws layout: Wqkvt 1.5MB | Wft 0.5MB | xs(/o) 64MB | v 64MB   (~136.3 MB)
  unsigned short* Wqkvt = (unsigned short*)ws;
  unsigned short* Wft   = (unsigned short*)(ws + 0x180000);
  unsigned short* xs    = (unsigned short*)(ws + 0x200000);
  unsigned short* vbuf  = (unsigned short*)(ws + 0x200000 + (size_t)B_ * S_ * C_ * 2);
  // q,k (bf16) use d_out as scratch: exactly 134,217,728 bytes, dead before proj_gn
  unsigned short* qbuf  = (unsigned short*)d_out;
  unsigned short* kbuf  = qbuf + (size_t)B_ * NH * S_ * DH;
  unsigned short* obuf  = xs;   // o overwrites xs (dead after qkv_gemm)
  float* out = (float*)d_out;

  hipLaunchKernelGGL(prep_w, dim3(8, 8, 4), dim3(256), 0, stream, Wq, Wk, Wv, Wf, Wqkvt, Wft);
  hipLaunchKernelGGL(prep_x, dim3(4, 8, 256), dim3(256), 0, stream, x, xs);
  hipLaunchKernelGGL(qkv_gemm, dim3(12, 2, 256), dim3(256), 0, stream,
                     xs, Wqkvt, bq, bk, bv, qbuf, kbuf, vbuf);
  hipLaunchKernelGGL(attn, dim3(8, 256), dim3(256), 0, stream, qbuf, kbuf, vbuf, obuf);
  hipLaunchKernelGGL(proj_gn, dim3(4, 256), dim3(512), 0, stream,
                     obuf, Wft, bf, x, gnw, gnb, out);
}

// Round 2
// 454.743 us; speedup vs baseline: 1.3787x; 1.3787x over previous
//
#include <hip/hip_runtime.h>
#include <hip/hip_bf16.h>
#include <stdint.h>

#define B_  256
#define C_  512
#define S_  256
#define NH  8
#define DH  64

typedef float f32x4 __attribute__((ext_vector_type(4)));
typedef short s16x8 __attribute__((ext_vector_type(8)));

static __device__ __forceinline__ unsigned short f2bf(float f) {
  union { float f; unsigned u; } v; v.f = f;
  unsigned r = v.u + 0x7FFFu + ((v.u >> 16) & 1u);
  return (unsigned short)(r >> 16);
}

static __device__ __forceinline__ unsigned pk_bf16(float lo, float hi) {
  unsigned r;
  asm("v_cvt_pk_bf16_f32 %0, %1, %2" : "=v"(r) : "v"(lo), "v"(hi));
  return r;
}

static __device__ __forceinline__ void gload_lds16(const void* g, void* l) {
  __builtin_amdgcn_global_load_lds((const __attribute__((address_space(1))) void*)g,
                                   (__attribute__((address_space(3))) void*)l,
                                   16, 0, 0);
}

// ---------------- prep_w: W [C][512] f32 -> W^T [512][C] bf16 -------------
__global__ __launch_bounds__(256) void prep_w(const float* __restrict__ Wq,
                                              const float* __restrict__ Wk,
                                              const float* __restrict__ Wv,
                                              const float* __restrict__ Wf,
                                              unsigned short* __restrict__ Wqkvt,
                                              unsigned short* __restrict__ Wft) {
  int mat = blockIdx.z;
  const float* src = (mat == 0) ? Wq : (mat == 1) ? Wk : (mat == 2) ? Wv : Wf;
  unsigned short* dst = (mat < 3) ? (Wqkvt + (size_t)mat * 512 * 512) : Wft;
  int n0 = blockIdx.x * 64, c0 = blockIdx.y * 64;
  __shared__ float tile[64][65];
  int t = threadIdx.x;
  int tr = t >> 4;          // 0..15
  int tc = (t & 15) * 4;    // 0..60
#pragma unroll
  for (int i = 0; i < 4; ++i) {
    int c = tr + i * 16;
    float4 v = *(const float4*)&src[(size_t)(c0 + c) * 512 + n0 + tc];
    tile[c][tc + 0] = v.x; tile[c][tc + 1] = v.y;
    tile[c][tc + 2] = v.z; tile[c][tc + 3] = v.w;
  }
  __syncthreads();
#pragma unroll
  for (int i = 0; i < 4; ++i) {
    int n = tr + i * 16;
    ushort4 o;
    o.x = f2bf(tile[tc + 0][n]); o.y = f2bf(tile[tc + 1][n]);
    o.z = f2bf(tile[tc + 2][n]); o.w = f2bf(tile[tc + 3][n]);
    *(ushort4*)&dst[(size_t)(n0 + n) * 512 + c0 + tc] = o;
  }
}

// ---------------- prep_x: x [B][C][S] f32 -> xs [B][S][C] bf16 ------------
__global__ __launch_bounds__(256) void prep_x(const float* __restrict__ x,
                                              unsigned short* __restrict__ xs) {
  int b = blockIdx.z, s0 = blockIdx.x * 64, c0 = blockIdx.y * 64;
  __shared__ float tile[64][65];
  int t = threadIdx.x;
  int tr = t >> 4, tc = (t & 15) * 4;
  const float* xb = x + (size_t)b * C_ * S_;
#pragma unroll
  for (int i = 0; i < 4; ++i) {
    int c = tr + i * 16;
    float4 v = *(const float4*)&xb[(size_t)(c0 + c) * S_ + s0 + tc];
    tile[c][tc + 0] = v.x; tile[c][tc + 1] = v.y;
    tile[c][tc + 2] = v.z; tile[c][tc + 3] = v.w;
  }
  __syncthreads();
  unsigned short* xsb = xs + (size_t)b * S_ * C_;
#pragma unroll
  for (int i = 0; i < 4; ++i) {
    int s = tr + i * 16;
    ushort4 o;
    o.x = f2bf(tile[tc + 0][s]); o.y = f2bf(tile[tc + 1][s]);
    o.z = f2bf(tile[tc + 2][s]); o.w = f2bf(tile[tc + 3][s]);
    *(ushort4*)&xsb[(size_t)(s0 + s) * C_ + c0 + tc] = o;
  }
}

// ---------------- qkv_gemm: [256 s x 512 c] @ [512 c x 1536 n] ------------
// tile 128x128, 4 waves (2x2), K-step 64. Q,K written [b][h][s][d];
// V written TRANSPOSED [b][h][d][s] for the attn PV A-operand.
__global__ __launch_bounds__(256) void qkv_gemm(const unsigned short* __restrict__ xs,
                                                const unsigned short* __restrict__ Wqkvt,
                                                const float* __restrict__ bq,
                                                const float* __restrict__ bk,
                                                const float* __restrict__ bv,
                                                unsigned short* __restrict__ qout,
                                                unsigned short* __restrict__ kout,
                                                unsigned short* __restrict__ vout) {
  int b = blockIdx.z, mt = blockIdx.y, nt = blockIdx.x;
  __shared__ unsigned short As[128 * 64];   // rows s, 64 k, swizzled
  __shared__ unsigned short Bs[128 * 64];   // rows n, 64 k, swizzled
  int t = threadIdx.x, lane = t & 63, w = t >> 6;
  int wr = w >> 1, wc = w & 1;
  f32x4 acc[4][4] = {};
  const unsigned short* xsb = xs + ((size_t)b * S_ + mt * 128) * C_;
  const unsigned short* wt = Wqkvt + (size_t)nt * 128 * C_;
  for (int ks = 0; ks < 8; ++ks) {
    __syncthreads();
#pragma unroll
    for (int i = 0; i < 4; ++i) {
      int ch = (w * 4 + i) * 64 + lane;
      int r = ch >> 3, g = ch & 7;
      int gs = g ^ (r & 7);
      gload_lds16(xsb + (size_t)r * C_ + ks * 64 + gs * 8, (char*)As + (w * 4 + i) * 1024);
      gload_lds16(wt + (size_t)r * C_ + ks * 64 + gs * 8, (char*)Bs + (w * 4 + i) * 1024);
    }
    __syncthreads();
#pragma unroll
    for (int kk = 0; kk < 2; ++kk) {
      s16x8 af[4], bfrag[4];
#pragma unroll
      for (int fi = 0; fi < 4; ++fi) {
        int r = wr * 64 + fi * 16 + (lane & 15);
        int slot = (kk * 4 + (lane >> 4)) ^ (r & 7);
        af[fi] = *(const s16x8*)((const char*)As + r * 128 + slot * 16);
      }
#pragma unroll
      for (int fj = 0; fj < 4; ++fj) {
        int r = wc * 64 + fj * 16 + (lane & 15);
        int slot = (kk * 4 + (lane >> 4)) ^ (r & 7);
        bfrag[fj] = *(const s16x8*)((const char*)Bs + r * 128 + slot * 16);
      }
#pragma unroll
      for (int fi = 0; fi < 4; ++fi)
#pragma unroll
        for (int fj = 0; fj < 4; ++fj)
          acc[fi][fj] = __builtin_amdgcn_mfma_f32_16x16x32_bf16(af[fi], bfrag[fj], acc[fi][fj], 0, 0, 0);
    }
  }
  // epilogue: +bias; q,k -> [B][NH][S][DH]; v -> [B][NH][DH][S] (transposed)
  int s_base = mt * 128 + wr * 64;
#pragma unroll
  for (int fj = 0; fj < 4; ++fj) {
    int n_glob = nt * 128 + wc * 64 + fj * 16;
    int sel = n_glob >> 9;
    int within = n_glob & 511;
    int h = within >> 6, dbase = within & 63;
    const float* bias = (sel == 0) ? bq : (sel == 1) ? bk : bv;
    float bias_v = bias[within + (lane & 15)];
    int d = dbase + (lane & 15);
    if (sel == 2) {
      unsigned short* vt = vout + (((size_t)b * NH + h) * DH + d) * (size_t)S_;
#pragma unroll
      for (int fi = 0; fi < 4; ++fi) {
        int srow = s_base + fi * 16 + (lane >> 4) * 4;
        ushort4 o4;
        o4.x = f2bf(acc[fi][fj][0] + bias_v);
        o4.y = f2bf(acc[fi][fj][1] + bias_v);
        o4.z = f2bf(acc[fi][fj][2] + bias_v);
        o4.w = f2bf(acc[fi][fj][3] + bias_v);
        *(ushort4*)&vt[srow] = o4;
      }
    } else {
      unsigned short* dst = (sel == 0) ? qout : kout;
      unsigned short* dhead = dst + ((size_t)b * NH + h) * S_ * DH;
#pragma unroll
      for (int fi = 0; fi < 4; ++fi) {
        int srow = s_base + fi * 16 + (lane >> 4) * 4;
#pragma unroll
        for (int rg = 0; rg < 4; ++rg)
          dhead[(size_t)(srow + rg) * DH + d] = f2bf(acc[fi][fj][rg] + bias_v);
      }
    }
  }
}

// ---------------- attn: swapped QK^T, in-register P, permuted-K LDS -------
// one block per (b,h): 8 waves x 32 q-rows. K rows permuted so the S^T
// D-registers are exactly PV's B-fragment k-slots (no cross-lane traffic).
__global__ __launch_bounds__(512, 4) void attn(const unsigned short* __restrict__ q,
                                               const unsigned short* __restrict__ k,
                                               const unsigned short* __restrict__ vt,
                                               unsigned short* __restrict__ o) {
  int h = blockIdx.x, b = blockIdx.y;
  const unsigned short* qh  = q  + ((size_t)b * NH + h) * S_ * DH;
  const unsigned short* kh  = k  + ((size_t)b * NH + h) * S_ * DH;
  const unsigned short* vth = vt + ((size_t)b * NH + h) * DH * S_;  // [64][256]
  __shared__ unsigned short Ks[2][64 * 72];   // permuted kv rows, pad 72
  __shared__ unsigned short Vs[2][64 * 72];   // rows d, cols kv, pad 72
  int t = threadIdx.x, lane = t & 63, w = t >> 6;
  int l15 = lane & 15, l4 = lane >> 4;

  // staging geometry: thread t copies one 16B chunk; K rows permuted by rho
  int r = t >> 3, g = t & 7;
  int w32 = r & 31;
  int rho = (r >> 5) * 32 + ((w32 >> 2) & 1) * 16 + (w32 >> 3) * 4 + (w32 & 3);

  // Q fragments resident (wave's 32 q-rows, as MFMA B-operand)
  s16x8 qf[2][2];
#pragma unroll
  for (int fi = 0; fi < 2; ++fi)
#pragma unroll
    for (int kk = 0; kk < 2; ++kk) {
      int row = w * 32 + fi * 16 + l15;
      qf[fi][kk] = *(const s16x8*)&qh[(size_t)row * DH + kk * 32 + l4 * 8];
    }

  f32x4 acco[4][2] = {};            // [d-tile][q-tile], O^T layout
  float m_run[2] = {-3e38f, -3e38f}, l_run[2] = {0.f, 0.f};
  const float SCL = 0.125f * 1.44269504089f;

  // prologue: stage kv-block 0
  {
    uint4 kv0 = *(const uint4*)(kh + (size_t)r * DH + g * 8);
    uint4 vv0 = *(const uint4*)(vth + (size_t)r * S_ + g * 8);
    *(uint4*)((char*)Ks[0] + rho * 144 + g * 16) = kv0;
    *(uint4*)((char*)Vs[0] + r * 144 + g * 16) = vv0;
  }
  __syncthreads();

  for (int kb = 0; kb < 4; ++kb) {
    int cur = kb & 1;
    // issue next block's global loads early (hidden under compute)
    uint4 kn, vn;
    if (kb < 3) {
      kn = *(const uint4*)(kh + (size_t)((kb + 1) * 64 + r) * DH + g * 8);
      vn = *(const uint4*)(vth + (size_t)r * S_ + (kb + 1) * 64 + g * 8);
    }
    // S^T = K(permuted) . Q^T
    f32x4 accs[4][2] = {};
#pragma unroll
    for (int kk = 0; kk < 2; ++kk) {
      s16x8 kf[4];
#pragma unroll
      for (int fj = 0; fj < 4; ++fj)
        kf[fj] = *(const s16x8*)((const char*)Ks[cur] + (fj * 16 + l15) * 144 + kk * 64 + l4 * 16);
#pragma unroll
      for (int fj = 0; fj < 4; ++fj)
#pragma unroll
        for (int fi = 0; fi < 2; ++fi)
          accs[fj][fi] = __builtin_amdgcn_mfma_f32_16x16x32_bf16(kf[fj], qf[fi][kk], accs[fj][fi], 0, 0, 0);
    }
    // online softmax: lane owns q-col (l15) per q-tile; kv spread 16 in-lane + quadrants
#pragma unroll
    for (int fi = 0; fi < 2; ++fi) {
      float mx = accs[0][fi][0];
#pragma unroll
      for (int fj = 0; fj < 4; ++fj)
#pragma unroll
        for (int rg = 0; rg < 4; ++rg) mx = fmaxf(mx, accs[fj][fi][rg]);
      mx = fmaxf(mx, __shfl_xor(mx, 16, 64));
      mx = fmaxf(mx, __shfl_xor(mx, 32, 64));
      float mnew = fmaxf(m_run[fi], mx);
      float alpha = __builtin_amdgcn_exp2f((m_run[fi] - mnew) * SCL);
      m_run[fi] = mnew;
      float lsum = 0.f;
#pragma unroll
      for (int fj = 0; fj < 4; ++fj)
#pragma unroll
        for (int rg = 0; rg < 4; ++rg) {
          float p = __builtin_amdgcn_exp2f((accs[fj][fi][rg] - mnew) * SCL);
          accs[fj][fi][rg] = p;
          lsum += p;
        }
      lsum += __shfl_xor(lsum, 16, 64);
      lsum += __shfl_xor(lsum, 32, 64);
      l_run[fi] = l_run[fi] * alpha + lsum;
#pragma unroll
      for (int fd = 0; fd < 4; ++fd)
#pragma unroll
        for (int rg = 0; rg < 4; ++rg) acco[fd][fi][rg] *= alpha;
    }
    // O^T += V^T . P : pack P in-lane (permutation makes regs = B-frag slots)
#pragma unroll
    for (int kk2 = 0; kk2 < 2; ++kk2) {
      s16x8 vf[4];
#pragma unroll
      for (int fd = 0; fd < 4; ++fd)
        vf[fd] = *(const s16x8*)((const char*)Vs[cur] + (fd * 16 + l15) * 144 + kk2 * 64 + l4 * 16);
#pragma unroll
      for (int fi = 0; fi < 2; ++fi) {
        union { unsigned u[4]; s16x8 v; } pb;
        pb.u[0] = pk_bf16(accs[2 * kk2][fi][0],     accs[2 * kk2][fi][1]);
        pb.u[1] = pk_bf16(accs[2 * kk2][fi][2],     accs[2 * kk2][fi][3]);
        pb.u[2] = pk_bf16(accs[2 * kk2 + 1][fi][0], accs[2 * kk2 + 1][fi][1]);
        pb.u[3] = pk_bf16(accs[2 * kk2 + 1][fi][2], accs[2 * kk2 + 1][fi][3]);
#pragma unroll
        for (int fd = 0; fd < 4; ++fd)
          acco[fd][fi] = __builtin_amdgcn_mfma_f32_16x16x32_bf16(vf[fd], pb.v, acco[fd][fi], 0, 0, 0);
      }
    }
    // write next block to the other LDS buffer, single barrier per iter
    if (kb < 3) {
      *(uint4*)((char*)Ks[cur ^ 1] + rho * 144 + g * 16) = kn;
      *(uint4*)((char*)Vs[cur ^ 1] + r * 144 + g * 16) = vn;
    }
    __syncthreads();
  }

  // epilogue: O^T regs -> o [B][S][C] bf16 (vectorized over d)
  unsigned short* ob = o + (size_t)b * S_ * C_ + h * DH;
#pragma unroll
  for (int fi = 0; fi < 2; ++fi) {
    float inv = 1.0f / l_run[fi];
    int qrow = w * 32 + fi * 16 + l15;
#pragma unroll
    for (int fd = 0; fd < 4; ++fd) {
      ushort4 s4;
      s4.x = f2bf(acco[fd][fi][0] * inv);
      s4.y = f2bf(acco[fd][fi][1] * inv);
      s4.z = f2bf(acco[fd][fi][2] * inv);
      s4.w = f2bf(acco[fd][fi][3] * inv);
      *(ushort4*)&ob[(size_t)qrow * C_ + fd * 16 + l4 * 4] = s4;
    }
  }
}

// ------------- proj_gn: y^T = Wf^T o^T (+bf +x), fused GroupNorm ----------
__global__ __launch_bounds__(512) void proj_gn(const unsigned short* __restrict__ o,
                                               const unsigned short* __restrict__ Wft,
                                               const float* __restrict__ bfp,
                                               const float* __restrict__ x,
                                               const float* __restrict__ gnw,
                                               const float* __restrict__ gnb,
                                               float* __restrict__ out) {
  int b = blockIdx.y, ct = blockIdx.x;
  __shared__ unsigned short As[128 * 72];   // Wf^T rows c
  __shared__ unsigned short Bs[256 * 72];   // o rows s
  __shared__ float red_s[128], red_q[128];
  __shared__ float mu_s[8], rs_s[8];
  int t = threadIdx.x, lane = t & 63, w = t >> 6;
  int wc = w >> 2, wsq = w & 3;
  if (t < 128) { red_s[t] = 0.f; red_q[t] = 0.f; }
  f32x4 acc[4][4] = {};
  const unsigned short* wt = Wft + (size_t)ct * 128 * C_;
  const unsigned short* ob = o + (size_t)b * S_ * C_;
  for (int ks = 0; ks < 8; ++ks) {
    __syncthreads();
#pragma unroll
    for (int i = 0; i < 2; ++i) {
      int ch = t + i * 512;
      int r = ch >> 3, g = ch & 7;
      *(uint4*)((char*)As + r * 144 + g * 16) =
          *(const uint4*)((const char*)(wt + (size_t)r * C_ + ks * 64) + g * 16);
    }
#pragma unroll
    for (int i = 0; i < 4; ++i) {
      int ch = t + i * 512;
      int r = ch >> 3, g = ch & 7;
      *(uint4*)((char*)Bs + r * 144 + g * 16) =
          *(const uint4*)((const char*)(ob + (size_t)r * C_ + ks * 64) + g * 16);
    }
    __syncthreads();
#pragma unroll
    for (int kk = 0; kk < 2; ++kk) {
      s16x8 af[4], bfrag[4];
#pragma unroll
      for (int fi = 0; fi < 4; ++fi) {
        int r = wc * 64 + fi * 16 + (lane & 15);
        af[fi] = *(const s16x8*)((const char*)As + r * 144 + kk * 64 + (lane >> 4) * 16);
      }
#pragma unroll
      for (int fj = 0; fj < 4; ++fj) {
        int r = wsq * 64 + fj * 16 + (lane & 15);
        bfrag[fj] = *(const s16x8*)((const char*)Bs + r * 144 + kk * 64 + (lane >> 4) * 16);
      }
#pragma unroll
      for (int fi = 0; fi < 4; ++fi)
#pragma unroll
        for (int fj = 0; fj < 4; ++fj)
          acc[fi][fj] = __builtin_amdgcn_mfma_f32_16x16x32_bf16(af[fi], bfrag[fj], acc[fi][fj], 0, 0, 0);
    }
  }
  const float* xb = x + (size_t)b * C_ * S_;
  int c_base = ct * 128 + wc * 64;
  int s_base = wsq * 64;
#pragma unroll
  for (int fi = 0; fi < 4; ++fi)
#pragma unroll
    for (int rg = 0; rg < 4; ++rg) {
      int c = c_base + fi * 16 + (lane >> 4) * 4 + rg;
      float bias_v = bfp[c];
      float psum = 0.f, psq = 0.f;
#pragma unroll
      for (int fj = 0; fj < 4; ++fj) {
        int s = s_base + fj * 16 + (lane & 15);
        float y = acc[fi][fj][rg] + bias_v + xb[(size_t)c * S_ + s];
        acc[fi][fj][rg] = y;
        psum += y; psq += y * y;
      }
#pragma unroll
      for (int off = 1; off < 16; off <<= 1) {
        psum += __shfl_xor(psum, off, 64);
        psq += __shfl_xor(psq, off, 64);
      }
      if ((lane & 15) == 0) {
        int cl = c - ct * 128;
        atomicAdd(&red_s[cl], psum);
        atomicAdd(&red_q[cl], psq);
      }
    }
  __syncthreads();
  if (t < 8) {
    float s = 0.f, qq = 0.f;
#pragma unroll
    for (int i = 0; i < 16; ++i) { s += red_s[t * 16 + i]; qq += red_q[t * 16 + i]; }
    float mu = s * (1.0f / 4096.0f);
    float var = qq * (1.0f / 4096.0f) - mu * mu;
    mu_s[t] = mu;
    rs_s[t] = rsqrtf(var + 1e-5f);
  }
  __syncthreads();
  float* outb = out + (size_t)b * C_ * S_;
#pragma unroll
  for (int fi = 0; fi < 4; ++fi)
#pragma unroll
    for (int rg = 0; rg < 4; ++rg) {
      int c = c_base + fi * 16 + (lane >> 4) * 4 + rg;
      int gl = (c - ct * 128) >> 4;
      float mu = mu_s[gl], rs = rs_s[gl];
      float gw = gnw[c], gb = gnb[c];
#pragma unroll
      for (int fj = 0; fj < 4; ++fj) {
        int s = s_base + fj * 16 + (lane & 15);
        outb[(size_t)c * S_ + s] = (acc[fi][fj][rg] - mu) * rs * gw + gb;
      }
    }
}

extern "C" void kernel_launch(void* const* d_in, const int* in_sizes, int n_in,
                              void* d_out, int out_size, void* d_ws, size_t ws_size,
                              hipStream_t stream) {
  const float* x   = (const float*)d_in[0];
  const float* Wq  = (const float*)d_in[1];
  const float* bq  = (const float*)d_in[2];
  const float* Wk  = (const float*)d_in[3];
  const float* bk  = (const float*)d_in[4];
  const float* Wv  = (const float*)d_in[5];
  const float* bv  = (const float*)d_in[6];
  const float* Wf  = (const float*)d_in[7];
  const float* bf  = (const float*)d_in[8];
  const float* gnw = (const float*)d_in[9];
  const float* gnb = (const float*)d_in[10];

  char* ws = (char*)d_ws;
  unsigned short* Wqkvt = (unsigned short*)ws;
  unsigned short* Wft   = (unsigned short*)(ws + 0x180000);
  unsigned short* xs    = (unsigned short*)(ws + 0x200000);
  unsigned short* vbuf  = (unsigned short*)(ws + 0x200000 + (size_t)B_ * S_ * C_ * 2);
  unsigned short* qbuf  = (unsigned short*)d_out;
  unsigned short* kbuf  = qbuf + (size_t)B_ * NH * S_ * DH;
  unsigned short* obuf  = xs;   // o overwrites xs (dead after qkv_gemm)
  float* out = (float*)d_out;

  hipLaunchKernelGGL(prep_w, dim3(8, 8, 4), dim3(256), 0, stream, Wq, Wk, Wv, Wf, Wqkvt, Wft);
  hipLaunchKernelGGL(prep_x, dim3(4, 8, 256), dim3(256), 0, stream, x, xs);
  hipLaunchKernelGGL(qkv_gemm, dim3(12, 2, 256), dim3(256), 0, stream,
                     xs, Wqkvt, bq, bk, bv, qbuf, kbuf, vbuf);
  hipLaunchKernelGGL(attn, dim3(8, 256), dim3(512), 0, stream, qbuf, kbuf, vbuf, obuf);
  hipLaunchKernelGGL(proj_gn, dim3(4, 256), dim3(512), 0, stream,
                     obuf, Wft, bf, x, gnw, gnb, out);
}